// Round 2
// baseline (726.363 us; speedup 1.0000x reference)
//
#include <hip/hip_runtime.h>

// GRU (reset_after, inference) + dense head, fully fused.
// B=1024 rows, T=512 steps, F=16, H=64.
// ONE ROW PER WAVE: 1024 blocks x 64 threads = 1024 waves = 1 wave/SIMD.
// lane j owns hidden unit j. No barriers in the t-loop (single wave/block).
// h broadcast: lane j writes hs[j] (ds_write), all lanes read hs as 16
// uniform-address ds_read_b128 broadcasts (LDS pipe, imm offsets).
// Full U (192 f32) + W (48 f32) pinned in VGPRs via empty-asm barriers so
// the allocator cannot sink the loads into the loop (R0 failure mode:
// VGPR_Count=96 -> weights re-loaded every step).

#define T_ 512
#define F_ 16
#define H_ 64

__device__ __forceinline__ float sigm(float a) {
    return 1.0f / (1.0f + __expf(-a));
}
__device__ __forceinline__ float tanh_fast(float a) {
    // tanh(a) = 1 - 2/(exp(2a)+1); saturates correctly for large |a|
    return 1.0f - 2.0f / (__expf(2.0f * a) + 1.0f);
}

__global__ __launch_bounds__(64, 1) void gru_fused(
    const float* __restrict__ x, const float* __restrict__ W,
    const float* __restrict__ U, const float* __restrict__ b,
    const float* __restrict__ w1, const float* __restrict__ b1,
    const float* __restrict__ gamma_, const float* __restrict__ beta_,
    const float* __restrict__ mmean, const float* __restrict__ mvar,
    const float* __restrict__ w2, const float* __restrict__ b2,
    float* __restrict__ out)
{
    __shared__ __align__(16) float hs[H_];   // 256 B

    const int j   = threadIdx.x;   // hidden unit 0..63
    const int row = blockIdx.x;

    // ---- full U and W fragments into VGPRs, pinned ----
    float uz[64], ur[64], uh[64];
    #pragma unroll
    for (int k = 0; k < 64; ++k) {
        uz[k] = U[k * 192 + j];
        ur[k] = U[k * 192 + 64 + j];
        uh[k] = U[k * 192 + 128 + j];
        asm volatile("" : "+v"(uz[k]), "+v"(ur[k]), "+v"(uh[k]));
    }
    float wz[16], wr[16], wh[16];
    #pragma unroll
    for (int f = 0; f < 16; ++f) {
        wz[f] = W[f * 192 + j];
        wr[f] = W[f * 192 + 64 + j];
        wh[f] = W[f * 192 + 128 + j];
        asm volatile("" : "+v"(wz[f]), "+v"(wr[f]), "+v"(wh[f]));
    }

    const float bz  = b[j]       + b[192 + j];   // bi_z + br_z
    const float brr = b[64 + j]  + b[256 + j];   // bi_r + br_r
    const float bxh = b[128 + j];                // bi_h (x-side)
    const float brh = b[320 + j];                // br_h (rec-side)

    const float4* xr4 = (const float4*)(x + (size_t)row * (T_ * F_));
    const float4* h4  = (const float4*)hs;

    // prefetch x_0 (wave-uniform address -> scalar/L2 load)
    float4 xq[4];
    #pragma unroll
    for (int i = 0; i < 4; ++i) xq[i] = xr4[i];

    float h = 0.0f;
    for (int t = 0; t < T_; ++t) {
        hs[j] = h;                         // ds_write; single wave, in-order DS

        // prefetch x_{t+1} while this step computes
        float4 xn[4];
        if (t + 1 < T_) {
            #pragma unroll
            for (int i = 0; i < 4; ++i) xn[i] = xr4[(t + 1) * 4 + i];
        }

        float az = bz, ar_ = brr, axh = bxh, arh = brh;

        // input projection (x_t uniform; 48 FMAs) — overlaps h write/read latency
        #pragma unroll
        for (int i = 0; i < 4; ++i) {
            az  = fmaf(xq[i].x, wz[4*i+0], az);
            az  = fmaf(xq[i].y, wz[4*i+1], az);
            az  = fmaf(xq[i].z, wz[4*i+2], az);
            az  = fmaf(xq[i].w, wz[4*i+3], az);
            ar_ = fmaf(xq[i].x, wr[4*i+0], ar_);
            ar_ = fmaf(xq[i].y, wr[4*i+1], ar_);
            ar_ = fmaf(xq[i].z, wr[4*i+2], ar_);
            ar_ = fmaf(xq[i].w, wr[4*i+3], ar_);
            axh = fmaf(xq[i].x, wh[4*i+0], axh);
            axh = fmaf(xq[i].y, wh[4*i+1], axh);
            axh = fmaf(xq[i].z, wh[4*i+2], axh);
            axh = fmaf(xq[i].w, wh[4*i+3], axh);
        }

        // recurrence: 16 x ds_read_b128 broadcast of h, 192 FMAs,
        // rolling prefetch depth 4
        float4 pf[4];
        #pragma unroll
        for (int c = 0; c < 4; ++c) pf[c] = h4[c];
        #pragma unroll
        for (int c = 0; c < 16; ++c) {
            float4 hv = pf[c & 3];
            if (c + 4 < 16) pf[c & 3] = h4[c + 4];
            az  = fmaf(hv.x, uz[4*c+0], az);
            az  = fmaf(hv.y, uz[4*c+1], az);
            az  = fmaf(hv.z, uz[4*c+2], az);
            az  = fmaf(hv.w, uz[4*c+3], az);
            ar_ = fmaf(hv.x, ur[4*c+0], ar_);
            ar_ = fmaf(hv.y, ur[4*c+1], ar_);
            ar_ = fmaf(hv.z, ur[4*c+2], ar_);
            ar_ = fmaf(hv.w, ur[4*c+3], ar_);
            arh = fmaf(hv.x, uh[4*c+0], arh);
            arh = fmaf(hv.y, uh[4*c+1], arh);
            arh = fmaf(hv.z, uh[4*c+2], arh);
            arh = fmaf(hv.w, uh[4*c+3], arh);
        }

        float z  = sigm(az);
        float r  = sigm(ar_);
        float hh = tanh_fast(fmaf(r, arh, axh));
        h = fmaf(z, h - hh, hh);

        #pragma unroll
        for (int i = 0; i < 4; ++i) xq[i] = xn[i];
    }

    // ---- head: y = relu(h @ w1 + b1); BN(inference); out = y @ w2 + b2 ----
    hs[j] = h;
    float y = b1[j];
    #pragma unroll
    for (int c = 0; c < 16; ++c) {
        float4 hv = h4[c];
        y = fmaf(hv.x, w1[(4*c+0) * 64 + j], y);
        y = fmaf(hv.y, w1[(4*c+1) * 64 + j], y);
        y = fmaf(hv.z, w1[(4*c+2) * 64 + j], y);
        y = fmaf(hv.w, w1[(4*c+3) * 64 + j], y);
    }
    y = fmaxf(y, 0.0f);
    y = fmaf((y - mmean[j]) * rsqrtf(mvar[j] + 1e-3f), gamma_[j], beta_[j]);

    float acc = y * w2[j];
    #pragma unroll
    for (int off = 32; off > 0; off >>= 1)
        acc += __shfl_down(acc, off, 64);
    if (j == 0) out[row] = acc + b2[0];
}

extern "C" void kernel_launch(void* const* d_in, const int* in_sizes, int n_in,
                              void* d_out, int out_size, void* d_ws, size_t ws_size,
                              hipStream_t stream) {
    const float* x      = (const float*)d_in[0];
    const float* W      = (const float*)d_in[1];
    const float* U      = (const float*)d_in[2];
    const float* b      = (const float*)d_in[3];
    const float* w1     = (const float*)d_in[4];
    const float* b1     = (const float*)d_in[5];
    const float* gamma_ = (const float*)d_in[6];
    const float* beta_  = (const float*)d_in[7];
    const float* mmean  = (const float*)d_in[8];
    const float* mvar   = (const float*)d_in[9];
    const float* w2     = (const float*)d_in[10];
    const float* b2     = (const float*)d_in[11];
    float* out = (float*)d_out;

    const int B = in_sizes[0] / (T_ * F_);   // 1024
    gru_fused<<<B, 64, 0, stream>>>(x, W, U, b, w1, b1, gamma_, beta_,
                                    mmean, mvar, w2, b2, out);
}

// Round 3
// 627.140 us; speedup vs baseline: 1.1582x; 1.1582x over previous
//
#include <hip/hip_runtime.h>

// GRU (reset_after, inference) + dense head, fully fused. fp32 VALU design.
// B=1024 rows, T=512 steps, F=16, H=64.
// One row per block of 128 threads (2 waves) -> 2048 waves = 2 waves/SIMD.
// lane j owns hidden unit j; the k-reduction (64) and f-reduction (16) are
// split across the 2 waves; partials combine via a parity double-buffered
// LDS slot with ONE barrier per step.
// Weights: per wave 120 floats (U-half 96, W-half 24) held in arch VGPRs,
// pinned by empty-asm "+v" constraints INSIDE the t-loop so the allocator
// cannot sink the loads (R0: VGPR=96, reloaded) or park them in AGPRs with
// per-use v_accvgpr_read (R1: VGPR=132, +355 inst/step).
// x_t: wave-uniform s_load into SGPRs (readfirstlane'd wave offset),
// prefetched one step ahead -> zero VALU/LDS cost for the x operand.

#define T_ 512
#define F_ 16
#define H_ 64

__device__ __forceinline__ float sigm(float a) {
    return 1.0f / (1.0f + __expf(-a));
}
__device__ __forceinline__ float tanh_fast(float a) {
    // tanh(a) = 1 - 2/(exp(2a)+1); saturates correctly for large |a|
    return 1.0f - 2.0f / (__expf(2.0f * a) + 1.0f);
}

__global__ __launch_bounds__(128, 2) void gru_fused(
    const float* __restrict__ x, const float* __restrict__ W,
    const float* __restrict__ U, const float* __restrict__ b,
    const float* __restrict__ w1, const float* __restrict__ b1,
    const float* __restrict__ gamma_, const float* __restrict__ beta_,
    const float* __restrict__ mmean, const float* __restrict__ mvar,
    const float* __restrict__ w2, const float* __restrict__ b2,
    float* __restrict__ out)
{
    __shared__ __align__(16) float comb[2 * 2 * 64 * 4];  // [parity][wave][lane][4]
    __shared__ __align__(16) float hs[H_];

    const int tid = threadIdx.x;
    const int j   = tid & 63;     // hidden unit
    const int w   = tid >> 6;     // wave id 0/1
    const int row = blockIdx.x;

    // ---- this wave's U k-half and W f-half into VGPRs ----
    float uz[32], ur[32], uh[32];
    const int k0 = w * 32;
    #pragma unroll
    for (int k = 0; k < 32; ++k) {
        uz[k] = U[(k0 + k) * 192 + j];
        ur[k] = U[(k0 + k) * 192 + 64 + j];
        uh[k] = U[(k0 + k) * 192 + 128 + j];
    }
    float wz[8], wr[8], wh[8];
    const int f0 = w * 8;
    #pragma unroll
    for (int f = 0; f < 8; ++f) {
        wz[f] = W[(f0 + f) * 192 + j];
        wr[f] = W[(f0 + f) * 192 + 64 + j];
        wh[f] = W[(f0 + f) * 192 + 128 + j];
    }
    // biases live only in wave 0's partial
    float bz = 0.f, brr = 0.f, bxh = 0.f, brh = 0.f;
    if (w == 0) {
        bz  = b[j]       + b[192 + j];   // bi_z + br_z
        brr = b[64 + j]  + b[256 + j];   // bi_r + br_r
        bxh = b[128 + j];                // bi_h (x-side)
        brh = b[320 + j];                // br_h (rec-side)
    }

    // ---- wave-uniform x pointer (values land in SGPRs via s_load) ----
    const int wu  = __builtin_amdgcn_readfirstlane(w);
    const int k0u = wu * 32;
    const float4* xp = (const float4*)(x + (size_t)row * (T_ * F_)) + wu * 2;
    float4 xa0 = xp[0], xa1 = xp[1];   // x_0, this wave's 8-float f-half

    float h = 0.0f;
    for (int t = 0; t < T_; ++t) {
        // pin the weights in arch VGPRs every iteration (zero instructions)
        #pragma unroll
        for (int k = 0; k < 32; ++k)
            asm volatile("" : "+v"(uz[k]), "+v"(ur[k]), "+v"(uh[k]));
        #pragma unroll
        for (int f = 0; f < 8; ++f)
            asm volatile("" : "+v"(wz[f]), "+v"(wr[f]), "+v"(wh[f]));

        // prefetch x_{t+1} (uniform s_load; hidden behind this step's FMAs)
        float4 xb0, xb1;
        if (t + 1 < T_) {
            xb0 = xp[(t + 1) * 4];
            xb1 = xp[(t + 1) * 4 + 1];
        }

        float az = bz, ar_ = brr, axh = bxh, arh = brh;

        // input projection: 24 FMAs, x operand in SGPRs
        {
            const float xv[8] = { xa0.x, xa0.y, xa0.z, xa0.w,
                                  xa1.x, xa1.y, xa1.z, xa1.w };
            #pragma unroll
            for (int f = 0; f < 8; ++f) {
                az  = fmaf(xv[f], wz[f], az);
                ar_ = fmaf(xv[f], wr[f], ar_);
                axh = fmaf(xv[f], wh[f], axh);
            }
        }

        // recurrence, this wave's k-half: h[k] via readlane (SGPR broadcast)
        {
            const int hb = __float_as_int(h);
            #pragma unroll
            for (int k = 0; k < 32; ++k) {
                float hk = __int_as_float(__builtin_amdgcn_readlane(hb, k0u + k));
                az  = fmaf(hk, uz[k], az);
                ar_ = fmaf(hk, ur[k], ar_);
                arh = fmaf(hk, uh[k], arh);
            }
        }

        // cross-wave combine (parity double-buffer; single barrier per step)
        const int p = t & 1;
        *(float4*)&comb[((p * 2 + w) * 64 + j) * 4] = make_float4(az, ar_, axh, arh);
        __syncthreads();
        const float4 o = *(const float4*)&comb[((p * 2 + (1 - w)) * 64 + j) * 4];
        az += o.x; ar_ += o.y; axh += o.z; arh += o.w;

        // gates (both waves redundantly; both need full h next step)
        const float z  = sigm(az);
        const float r  = sigm(ar_);
        const float hh = tanh_fast(fmaf(r, arh, axh));
        h = fmaf(z, h - hh, hh);

        xa0 = xb0; xa1 = xb1;
    }

    hs[j] = h;            // both waves write identical values (benign)
    __syncthreads();

    // ---- head: y = relu(h @ w1 + b1); BN(inference); out = y @ w2 + b2 ----
    const float4* h4 = (const float4*)hs;
    float y = b1[j];
    #pragma unroll
    for (int c = 0; c < 16; ++c) {
        const float4 hv = h4[c];
        y = fmaf(hv.x, w1[(4 * c + 0) * 64 + j], y);
        y = fmaf(hv.y, w1[(4 * c + 1) * 64 + j], y);
        y = fmaf(hv.z, w1[(4 * c + 2) * 64 + j], y);
        y = fmaf(hv.w, w1[(4 * c + 3) * 64 + j], y);
    }
    y = fmaxf(y, 0.0f);
    y = fmaf((y - mmean[j]) * rsqrtf(mvar[j] + 1e-3f), gamma_[j], beta_[j]);

    float acc = y * w2[j];
    #pragma unroll
    for (int off = 32; off > 0; off >>= 1)
        acc += __shfl_down(acc, off, 64);
    if (tid == 0) out[row] = acc + b2[0];
}

extern "C" void kernel_launch(void* const* d_in, const int* in_sizes, int n_in,
                              void* d_out, int out_size, void* d_ws, size_t ws_size,
                              hipStream_t stream) {
    const float* x      = (const float*)d_in[0];
    const float* W      = (const float*)d_in[1];
    const float* U      = (const float*)d_in[2];
    const float* b      = (const float*)d_in[3];
    const float* w1     = (const float*)d_in[4];
    const float* b1     = (const float*)d_in[5];
    const float* gamma_ = (const float*)d_in[6];
    const float* beta_  = (const float*)d_in[7];
    const float* mmean  = (const float*)d_in[8];
    const float* mvar   = (const float*)d_in[9];
    const float* w2     = (const float*)d_in[10];
    const float* b2     = (const float*)d_in[11];
    float* out = (float*)d_out;

    const int B = in_sizes[0] / (T_ * F_);   // 1024
    gru_fused<<<B, 128, 0, stream>>>(x, W, U, b, w1, b1, gamma_, beta_,
                                     mmean, mvar, w2, b2, out);
}

// Round 4
// 558.954 us; speedup vs baseline: 1.2995x; 1.1220x over previous
//
#include <hip/hip_runtime.h>

// GRU (reset_after, inference) + dense head, fully fused. fp32 VALU design.
// B=1024 rows, T=512 steps, F=16, H=64.
// One row per block of 128 threads (2 waves) -> 2048 waves = 2 waves/SIMD,
// grid fits in ONE residency pass (4 blocks/CU).
// lane j owns hidden unit j; k-reduction (64) and f-reduction (16) split
// across the 2 waves; partials combine via parity double-buffered LDS slot,
// ONE barrier per step.
//
// KEY FIX (R0/R1/R2 post-mortem): the AMDGPU RA targets high occupancy
// heuristically (it allocated 92-96 VGPRs every round and spilled/
// rematerialized the 120 resident weight floats). __launch_bounds__'s 2nd
// arg only sets a cap; amdgpu_waves_per_eu(2,2) additionally clamps the
// occupancy TARGET to 2 waves/EU, granting the full 256-VGPR budget so the
// ~150-value live set stays in registers. No asm pinning (R2 showed pinned
// non-remat values get spilled to scratch when the target is low).
// Tripwire: VGPR_Count must come back >= ~150.

#define T_ 512
#define F_ 16
#define H_ 64

__device__ __forceinline__ float sigm(float a) {
    return 1.0f / (1.0f + __expf(-a));
}
__device__ __forceinline__ float tanh_fast(float a) {
    // tanh(a) = 1 - 2/(exp(2a)+1); saturates correctly for large |a|
    return 1.0f - 2.0f / (__expf(2.0f * a) + 1.0f);
}

__global__ __launch_bounds__(128)
__attribute__((amdgpu_waves_per_eu(2, 2)))
void gru_fused(
    const float* __restrict__ x, const float* __restrict__ W,
    const float* __restrict__ U, const float* __restrict__ b,
    const float* __restrict__ w1, const float* __restrict__ b1,
    const float* __restrict__ gamma_, const float* __restrict__ beta_,
    const float* __restrict__ mmean, const float* __restrict__ mvar,
    const float* __restrict__ w2, const float* __restrict__ b2,
    float* __restrict__ out)
{
    __shared__ __align__(16) float comb[2 * 2 * 64 * 4];  // [parity][wave][lane][4]
    __shared__ __align__(16) float hs[H_];

    const int tid = threadIdx.x;
    const int j   = tid & 63;     // hidden unit
    const int w   = tid >> 6;     // wave id 0/1
    const int row = blockIdx.x;

    // ---- this wave's U k-half and W f-half into VGPRs ----
    float uz[32], ur[32], uh[32];
    const int k0 = w * 32;
    #pragma unroll
    for (int k = 0; k < 32; ++k) {
        uz[k] = U[(k0 + k) * 192 + j];
        ur[k] = U[(k0 + k) * 192 + 64 + j];
        uh[k] = U[(k0 + k) * 192 + 128 + j];
    }
    float wz[8], wr[8], wh[8];
    const int f0 = w * 8;
    #pragma unroll
    for (int f = 0; f < 8; ++f) {
        wz[f] = W[(f0 + f) * 192 + j];
        wr[f] = W[(f0 + f) * 192 + 64 + j];
        wh[f] = W[(f0 + f) * 192 + 128 + j];
    }
    // biases live only in wave 0's partial
    float bz = 0.f, brr = 0.f, bxh = 0.f, brh = 0.f;
    if (w == 0) {
        bz  = b[j]       + b[192 + j];   // bi_z + br_z
        brr = b[64 + j]  + b[256 + j];   // bi_r + br_r
        bxh = b[128 + j];                // bi_h (x-side)
        brh = b[320 + j];                // br_h (rec-side)
    }

    // ---- wave-uniform x pointer (values land in SGPRs via s_load) ----
    const int wu  = __builtin_amdgcn_readfirstlane(w);
    const int k0u = wu * 32;
    const float4* xp = (const float4*)(x + (size_t)row * (T_ * F_)) + wu * 2;
    float4 xa0 = xp[0], xa1 = xp[1];   // x_0, this wave's 8-float f-half

    float h = 0.0f;
    for (int t = 0; t < T_; ++t) {
        // prefetch x_{t+1} (uniform s_load; hidden behind this step's FMAs)
        float4 xb0, xb1;
        if (t + 1 < T_) {
            xb0 = xp[(t + 1) * 4];
            xb1 = xp[(t + 1) * 4 + 1];
        }

        float az = bz, ar_ = brr, axh = bxh, arh = brh;

        // input projection: 24 FMAs, x operand in SGPRs
        {
            const float xv[8] = { xa0.x, xa0.y, xa0.z, xa0.w,
                                  xa1.x, xa1.y, xa1.z, xa1.w };
            #pragma unroll
            for (int f = 0; f < 8; ++f) {
                az  = fmaf(xv[f], wz[f], az);
                ar_ = fmaf(xv[f], wr[f], ar_);
                axh = fmaf(xv[f], wh[f], axh);
            }
        }

        // recurrence, this wave's k-half: h[k] via readlane (SGPR broadcast)
        {
            const int hb = __float_as_int(h);
            #pragma unroll
            for (int k = 0; k < 32; ++k) {
                float hk = __int_as_float(__builtin_amdgcn_readlane(hb, k0u + k));
                az  = fmaf(hk, uz[k], az);
                ar_ = fmaf(hk, ur[k], ar_);
                arh = fmaf(hk, uh[k], arh);
            }
        }

        // cross-wave combine (parity double-buffer; single barrier per step)
        const int p = t & 1;
        *(float4*)&comb[((p * 2 + w) * 64 + j) * 4] = make_float4(az, ar_, axh, arh);
        __syncthreads();
        const float4 o = *(const float4*)&comb[((p * 2 + (1 - w)) * 64 + j) * 4];
        az += o.x; ar_ += o.y; axh += o.z; arh += o.w;

        // gates (both waves redundantly; both need full h next step)
        const float z  = sigm(az);
        const float r  = sigm(ar_);
        const float hh = tanh_fast(fmaf(r, arh, axh));
        h = fmaf(z, h - hh, hh);

        xa0 = xb0; xa1 = xb1;
    }

    hs[j] = h;            // both waves write identical values (benign)
    __syncthreads();

    // ---- head: y = relu(h @ w1 + b1); BN(inference); out = y @ w2 + b2 ----
    const float4* h4 = (const float4*)hs;
    float y = b1[j];
    #pragma unroll
    for (int c = 0; c < 16; ++c) {
        const float4 hv = h4[c];
        y = fmaf(hv.x, w1[(4 * c + 0) * 64 + j], y);
        y = fmaf(hv.y, w1[(4 * c + 1) * 64 + j], y);
        y = fmaf(hv.z, w1[(4 * c + 2) * 64 + j], y);
        y = fmaf(hv.w, w1[(4 * c + 3) * 64 + j], y);
    }
    y = fmaxf(y, 0.0f);
    y = fmaf((y - mmean[j]) * rsqrtf(mvar[j] + 1e-3f), gamma_[j], beta_[j]);

    float acc = y * w2[j];
    #pragma unroll
    for (int off = 32; off > 0; off >>= 1)
        acc += __shfl_down(acc, off, 64);
    if (tid == 0) out[row] = acc + b2[0];
}

extern "C" void kernel_launch(void* const* d_in, const int* in_sizes, int n_in,
                              void* d_out, int out_size, void* d_ws, size_t ws_size,
                              hipStream_t stream) {
    const float* x      = (const float*)d_in[0];
    const float* W      = (const float*)d_in[1];
    const float* U      = (const float*)d_in[2];
    const float* b      = (const float*)d_in[3];
    const float* w1     = (const float*)d_in[4];
    const float* b1     = (const float*)d_in[5];
    const float* gamma_ = (const float*)d_in[6];
    const float* beta_  = (const float*)d_in[7];
    const float* mmean  = (const float*)d_in[8];
    const float* mvar   = (const float*)d_in[9];
    const float* w2     = (const float*)d_in[10];
    const float* b2     = (const float*)d_in[11];
    float* out = (float*)d_out;

    const int B = in_sizes[0] / (T_ * F_);   // 1024
    gru_fused<<<B, 128, 0, stream>>>(x, W, U, b, w1, b1, gamma_, beta_,
                                     mmean, mvar, w2, b2, out);
}